// Round 3
// baseline (284.016 us; speedup 1.0000x reference)
//
#include <hip/hip_runtime.h>
#include <hip/hip_bf16.h>

typedef __attribute__((ext_vector_type(8))) short short8;
typedef __attribute__((ext_vector_type(4))) float floatx4;

#define NN     4096
#define DIN    128
#define EDIM   192
#define DMODEL 128

__device__ __forceinline__ unsigned short f2bf(float f) {
    union { float f; unsigned int i; } x; x.f = f;
    unsigned int u = x.i;
    u += 0x7FFFu + ((u >> 16) & 1u);   // RNE
    return (unsigned short)(u >> 16);
}

__device__ __forceinline__ unsigned int pk2(float lo, float hi) {
    union { __hip_bfloat162 v; unsigned int u; } cv;
    cv.v = __float22bfloat162_rn(make_float2(lo, hi));
    return cv.u;
}

__device__ __forceinline__ short8 cvt8(const float4 a, const float4 b) {
    union { short8 s; unsigned int u[4]; } r;
    r.u[0] = pk2(a.x, a.y);
    r.u[1] = pk2(a.z, a.w);
    r.u[2] = pk2(b.x, b.y);
    r.u[3] = pk2(b.z, b.w);
    return r.s;
}

// Pack W (576x128 fp32, row-major, original k = 3c+j feat / 384+e edge) into
// bf16 MFMA B-fragment order under PERMUTED k-order kt = j*128+c (feat), kt=k (edge):
// wf[((gs*8+ct)*64+lane)*8+jj] = bf16(W[korig(kt)*128 + ct*16 + (lane&15)]),
// kt = gs*32 + (lane>>4)*8 + jj.
__global__ void prep_w(const float* __restrict__ W, unsigned short* __restrict__ wf) {
    const int t = blockIdx.x * 256 + threadIdx.x;      // 288*256 == 73728 exactly
    const int jj   = t & 7;
    const int lane = (t >> 3) & 63;
    const int ct   = (t >> 9) & 7;
    const int gs   = t >> 12;
    const int kt = gs * 32 + ((lane >> 4) << 3) + jj;
    const int korig = (kt < 384) ? ((kt & 127) * 3 + (kt >> 7)) : kt;
    const int n = ct * 16 + (lane & 15);
    wf[t] = f2bf(W[korig * DMODEL + n]);
}

// Windowed mask max: m3[p,i] = max(mask[p,i..i+2]) with zero pad past N. Exact fp32.
__global__ void prep_m(const float* __restrict__ mask,
                       float* __restrict__ m3f, float* __restrict__ o_m) {
    const int t = blockIdx.x * 256 + threadIdx.x;      // 64*256 == 16384 exactly
    const int i = t & (NN - 1);
    float v = mask[t];
    if (i + 1 < NN) v = fmaxf(v, mask[t + 1]);
    if (i + 2 < NN) v = fmaxf(v, mask[t + 2]);
    m3f[t] = v;
    o_m[t] = v;
}

// adj passthrough: float4 grid-stride copy (4096*4096 floats = 4194304 float4)
__global__ __launch_bounds__(256) void copy_adj(const float4* __restrict__ src,
                                                float4* __restrict__ dst) {
    int idx = blockIdx.x * 256 + threadIdx.x;          // 1024 blocks -> 262144 threads
    #pragma unroll
    for (int i = 0; i < 16; ++i)
        dst[idx + i * 262144] = src[idx + i * 262144];
}

// Main fused kernel, LDS-free / barrier-free:
// block = 4 waves, 128 rows (wave wv: rows wv*32 + rt*16 + (lane&15)), 128 cols.
// K permuted to kt = j*128+c (feat) then edge; A-fragments are direct global
// float4x2 loads + packed bf16 convert; B-fragments from L2-resident wfrag.
__global__ __launch_bounds__(256, 2) void main_k(
    const float* __restrict__ feat,
    const float* __restrict__ edgef,
    const unsigned short* __restrict__ wfrag,
    const float* __restrict__ bias,
    const float* __restrict__ m3f,
    float* __restrict__ o_res,
    float* __restrict__ o_out)
{
    const int tid  = threadIdx.x;
    const int lane = tid & 63;
    const int wv   = tid >> 6;
    const int nn   = lane & 15;
    const int quad = lane >> 4;

    const int blk = blockIdx.x;
    const int b   = blk >> 5;
    const int i0  = (blk & 31) << 7;

    const float* fb = feat  + (size_t)b * NN * DIN;
    const float* eb = edgef + (size_t)b * NN * EDIM;

    const int rowb = i0 + wv * 32 + nn;    // A-row base for this lane (rt adds 16)

    floatx4 acc[2][8];
    #pragma unroll
    for (int rt = 0; rt < 2; ++rt)
        #pragma unroll
        for (int ct = 0; ct < 8; ++ct)
            acc[rt][ct] = (floatx4){0.f, 0.f, 0.f, 0.f};

    const short8* wf8 = (const short8*)wfrag;

    // ---- feature K region: kt = j*128 + sl*32 + quad*8 + jj ----
    #pragma unroll
    for (int j = 0; j < 3; ++j) {
        #pragma unroll
        for (int sl = 0; sl < 4; ++sl) {
            const int gs = j * 4 + sl;
            short8 bfr[8];
            #pragma unroll
            for (int ct = 0; ct < 8; ++ct)
                bfr[ct] = wf8[(gs * 8 + ct) * 64 + lane];
            short8 afr[2];
            #pragma unroll
            for (int rt = 0; rt < 2; ++rt) {
                const int row = rowb + rt * 16 + j;
                float4 a0 = make_float4(0.f, 0.f, 0.f, 0.f);
                float4 a1 = a0;
                if (row < NN) {
                    const float* s = fb + (size_t)row * DIN + sl * 32 + quad * 8;
                    a0 = *(const float4*)s;
                    a1 = *(const float4*)(s + 4);
                }
                afr[rt] = cvt8(a0, a1);
            }
            #pragma unroll
            for (int rt = 0; rt < 2; ++rt)
                #pragma unroll
                for (int ct = 0; ct < 8; ++ct)
                    acc[rt][ct] = __builtin_amdgcn_mfma_f32_16x16x32_bf16(
                        afr[rt], bfr[ct], acc[rt][ct], 0, 0, 0);
        }
    }

    // ---- edge K region: kt = 384 + eg*32 + quad*8 + jj ----
    #pragma unroll
    for (int eg = 0; eg < 6; ++eg) {
        const int gs = 12 + eg;
        short8 bfr[8];
        #pragma unroll
        for (int ct = 0; ct < 8; ++ct)
            bfr[ct] = wf8[(gs * 8 + ct) * 64 + lane];
        short8 afr[2];
        #pragma unroll
        for (int rt = 0; rt < 2; ++rt) {
            const int row = rowb + rt * 16;            // always < NN
            const float* s = eb + (size_t)row * EDIM + eg * 32 + quad * 8;
            const float4 a0 = *(const float4*)s;
            const float4 a1 = *(const float4*)(s + 4);
            afr[rt] = cvt8(a0, a1);
        }
        #pragma unroll
        for (int rt = 0; rt < 2; ++rt)
            #pragma unroll
            for (int ct = 0; ct < 8; ++ct)
                acc[rt][ct] = __builtin_amdgcn_mfma_f32_16x16x32_bf16(
                    afr[rt], bfr[ct], acc[rt][ct], 0, 0, 0);
    }

    // ---- epilogue: bias + ReLU, jump (3-row feature mean), mask, fp32 stores ----
    float biasv[8];
    #pragma unroll
    for (int ct = 0; ct < 8; ++ct)
        biasv[ct] = bias[ct * 16 + nn];

    const int   p    = b & 3;
    const float inv3 = 1.0f / 3.0f;

    #pragma unroll
    for (int rt = 0; rt < 2; ++rt) {
        const int rbase = wv * 32 + rt * 16 + quad * 4;   // C/D: row = quad*4 + reg
        float mv[4];
        #pragma unroll
        for (int reg = 0; reg < 4; ++reg)
            mv[reg] = m3f[p * NN + i0 + rbase + reg];
        #pragma unroll
        for (int ct = 0; ct < 8; ++ct) {
            const int col = ct * 16 + nn;                 // C/D: col = lane&15
            float fv[6];
            #pragma unroll
            for (int t6 = 0; t6 < 6; ++t6) {
                const int row = i0 + rbase + t6;
                fv[t6] = (row < NN) ? fb[(size_t)row * DIN + col] : 0.f;
            }
            #pragma unroll
            for (int reg = 0; reg < 4; ++reg) {
                float o = acc[rt][ct][reg] + biasv[ct];
                o = fmaxf(o, 0.f);
                const float jmp = (fv[reg] + fv[reg + 1] + fv[reg + 2]) * inv3;
                const size_t off = ((size_t)b * NN + (i0 + rbase + reg)) * DMODEL + col;
                const float mm = mv[reg];
                o_out[off] = mm * o;
                o_res[off] = mm * (o + jmp);
            }
        }
    }
}

extern "C" void kernel_launch(void* const* d_in, const int* in_sizes, int n_in,
                              void* d_out, int out_size, void* d_ws, size_t ws_size,
                              hipStream_t stream) {
    const float* adj   = (const float*)d_in[0];
    const float* feat  = (const float*)d_in[1];
    const float* edgef = (const float*)d_in[2];
    const float* mask  = (const float*)d_in[3];
    const float* W     = (const float*)d_in[4];
    const float* bias  = (const float*)d_in[5];

    float* out   = (float*)d_out;
    float* o_adj = out;
    float* o_res = out + (size_t)16777216;              // 4096*4096
    float* o_out = o_res + (size_t)8388608;             // 16*4096*128
    float* o_m   = o_out + (size_t)8388608;             // + 16*4096*128 -> 4*4096 tail

    unsigned short* wfrag = (unsigned short*)d_ws;               // 73728 * 2 B
    float*          m3f   = (float*)((char*)d_ws + 73728 * 2);   // 16384 * 4 B

    copy_adj<<<1024, 256, 0, stream>>>((const float4*)adj, (float4*)o_adj);
    prep_w<<<288, 256, 0, stream>>>(W, wfrag);
    prep_m<<<64, 256, 0, stream>>>(mask, m3f, o_m);
    main_k<<<512, 256, 0, stream>>>(feat, edgef, wfrag, bias, m3f, o_res, o_out);
}

// Round 5
// 273.656 us; speedup vs baseline: 1.0379x; 1.0379x over previous
//
#include <hip/hip_runtime.h>
#include <hip/hip_bf16.h>

typedef __attribute__((ext_vector_type(8))) short short8;
typedef __attribute__((ext_vector_type(4))) float floatx4;

#define NN     4096
#define DIN    128
#define EDIM   192
#define DMODEL 128

__device__ __forceinline__ unsigned short f2bf(float f) {
    union { float f; unsigned int i; } x; x.f = f;
    unsigned int u = x.i;
    u += 0x7FFFu + ((u >> 16) & 1u);   // RNE
    return (unsigned short)(u >> 16);
}

__device__ __forceinline__ unsigned int pk2(float lo, float hi) {
    union { __hip_bfloat162 v; unsigned int u; } cv;
    cv.v = __float22bfloat162_rn(make_float2(lo, hi));
    return cv.u;
}

__device__ __forceinline__ short8 cvt8(const float4 a, const float4 b) {
    union { short8 s; unsigned int u[4]; } r;
    r.u[0] = pk2(a.x, a.y);
    r.u[1] = pk2(a.z, a.w);
    r.u[2] = pk2(b.x, b.y);
    r.u[3] = pk2(b.z, b.w);
    return r.s;
}

// Pack W (576x128 fp32, row-major, original k = 3c+j feat / 384+e edge) into
// bf16 MFMA B-fragment order under PERMUTED k-order kt = j*128+c (feat), kt=k (edge):
// wf[((gs*8+ct)*64+lane)*8+jj] = bf16(W[korig(kt)*128 + ct*16 + (lane&15)]),
// kt = gs*32 + (lane>>4)*8 + jj.
__global__ void prep_w(const float* __restrict__ W, unsigned short* __restrict__ wf) {
    const int t = blockIdx.x * 256 + threadIdx.x;      // 288*256 == 73728 exactly
    const int jj   = t & 7;
    const int lane = (t >> 3) & 63;
    const int ct   = (t >> 9) & 7;
    const int gs   = t >> 12;
    const int kt = gs * 32 + ((lane >> 4) << 3) + jj;
    const int korig = (kt < 384) ? ((kt & 127) * 3 + (kt >> 7)) : kt;
    const int n = ct * 16 + (lane & 15);
    wf[t] = f2bf(W[korig * DMODEL + n]);
}

// Fully fused main kernel (one launch does GEMM+epilogue, m3/o_m, and adj copy):
// block = 4 waves, 128 rows of batch b, 128 cols. LDS only for the 128 m3 values.
__global__ __launch_bounds__(256, 2) void main_k(
    const float* __restrict__ feat,
    const float* __restrict__ edgef,
    const unsigned short* __restrict__ wfrag,
    const float* __restrict__ bias,
    const float* __restrict__ mask,
    const floatx4* __restrict__ adj4,
    floatx4* __restrict__ o_adj4,
    float* __restrict__ o_res,
    float* __restrict__ o_out,
    float* __restrict__ o_m)
{
    __shared__ float m3s[128];

    const int tid  = threadIdx.x;
    const int lane = tid & 63;
    const int wv   = tid >> 6;
    const int nn   = lane & 15;
    const int quad = lane >> 4;

    const int blk = blockIdx.x;
    const int b   = blk >> 5;
    const int i0  = (blk & 31) << 7;
    const int p   = b & 3;

    // ---- m3 (3-window mask max) into LDS; blocks b<4 also emit output 3 ----
    if (tid < 128) {
        const int i = i0 + tid;
        float v = mask[p * NN + i];
        if (i + 1 < NN) v = fmaxf(v, mask[p * NN + i + 1]);
        if (i + 2 < NN) v = fmaxf(v, mask[p * NN + i + 2]);
        m3s[tid] = v;
        if (b < 4) o_m[p * NN + i] = v;
    }
    __syncthreads();

    const float* fb = feat  + (size_t)b * NN * DIN;
    const float* eb = edgef + (size_t)b * NN * EDIM;

    const int rowb = i0 + wv * 32 + nn;    // A-row base for this lane (rt adds 16)

    floatx4 acc[2][8];
    #pragma unroll
    for (int rt = 0; rt < 2; ++rt)
        #pragma unroll
        for (int ct = 0; ct < 8; ++ct)
            acc[rt][ct] = (floatx4){0.f, 0.f, 0.f, 0.f};

    const short8* wf8 = (const short8*)wfrag;

    // ---- feature K region: kt = j*128 + sl*32 + quad*8 + jj ----
    #pragma unroll
    for (int j = 0; j < 3; ++j) {
        #pragma unroll
        for (int sl = 0; sl < 4; ++sl) {
            const int gs = j * 4 + sl;
            short8 bfr[8];
            #pragma unroll
            for (int ct = 0; ct < 8; ++ct)
                bfr[ct] = wf8[(gs * 8 + ct) * 64 + lane];
            short8 afr[2];
            #pragma unroll
            for (int rt = 0; rt < 2; ++rt) {
                const int row = rowb + rt * 16 + j;
                float4 a0 = make_float4(0.f, 0.f, 0.f, 0.f);
                float4 a1 = a0;
                if (row < NN) {
                    const float* s = fb + (size_t)row * DIN + sl * 32 + quad * 8;
                    a0 = *(const float4*)s;
                    a1 = *(const float4*)(s + 4);
                }
                afr[rt] = cvt8(a0, a1);
            }
            #pragma unroll
            for (int rt = 0; rt < 2; ++rt)
                #pragma unroll
                for (int ct = 0; ct < 8; ++ct)
                    acc[rt][ct] = __builtin_amdgcn_mfma_f32_16x16x32_bf16(
                        afr[rt], bfr[ct], acc[rt][ct], 0, 0, 0);
        }
    }

    // ---- edge K region: kt = 384 + eg*32 + quad*8 + jj ----
    #pragma unroll
    for (int eg = 0; eg < 6; ++eg) {
        const int gs = 12 + eg;
        short8 bfr[8];
        #pragma unroll
        for (int ct = 0; ct < 8; ++ct)
            bfr[ct] = wf8[(gs * 8 + ct) * 64 + lane];
        short8 afr[2];
        #pragma unroll
        for (int rt = 0; rt < 2; ++rt) {
            const int row = rowb + rt * 16;            // always < NN
            const float* s = eb + (size_t)row * EDIM + eg * 32 + quad * 8;
            const float4 a0 = *(const float4*)s;
            const float4 a1 = *(const float4*)(s + 4);
            afr[rt] = cvt8(a0, a1);
        }
        #pragma unroll
        for (int rt = 0; rt < 2; ++rt)
            #pragma unroll
            for (int ct = 0; ct < 8; ++ct)
                acc[rt][ct] = __builtin_amdgcn_mfma_f32_16x16x32_bf16(
                    afr[rt], bfr[ct], acc[rt][ct], 0, 0, 0);
    }

    // ---- epilogue: bias + ReLU, jump (3-row feature mean), mask, fp32 stores ----
    float biasv[8];
    #pragma unroll
    for (int ct = 0; ct < 8; ++ct)
        biasv[ct] = bias[ct * 16 + nn];

    const float inv3 = 1.0f / 3.0f;

    #pragma unroll
    for (int rt = 0; rt < 2; ++rt) {
        const int rbase = wv * 32 + rt * 16 + quad * 4;   // C/D: row = quad*4 + reg
        float mv[4];
        #pragma unroll
        for (int reg = 0; reg < 4; ++reg)
            mv[reg] = m3s[rbase + reg];
        #pragma unroll
        for (int ct = 0; ct < 8; ++ct) {
            const int col = ct * 16 + nn;                 // C/D: col = lane&15
            float fv[6];
            #pragma unroll
            for (int t6 = 0; t6 < 6; ++t6) {
                const int row = i0 + rbase + t6;
                fv[t6] = (row < NN) ? fb[(size_t)row * DIN + col] : 0.f;
            }
            #pragma unroll
            for (int reg = 0; reg < 4; ++reg) {
                float o = acc[rt][ct][reg] + biasv[ct];
                o = fmaxf(o, 0.f);
                const float jmp = (fv[reg] + fv[reg + 1] + fv[reg + 2]) * inv3;
                const size_t off = ((size_t)b * NN + (i0 + rbase + reg)) * DMODEL + col;
                const float mm = mv[reg];
                __builtin_nontemporal_store(mm * o, &o_out[off]);
                __builtin_nontemporal_store(mm * (o + jmp), &o_res[off]);
            }
        }
    }

    // ---- adj passthrough slice: 512 blocks x 256 thr x 32 float4 = 4096*4096 ----
    {
        const int idx = blk * 256 + tid;                  // 131072 threads
        #pragma unroll
        for (int i = 0; i < 32; ++i) {
            const floatx4 v = __builtin_nontemporal_load(&adj4[idx + i * 131072]);
            __builtin_nontemporal_store(v, &o_adj4[idx + i * 131072]);
        }
    }
}

extern "C" void kernel_launch(void* const* d_in, const int* in_sizes, int n_in,
                              void* d_out, int out_size, void* d_ws, size_t ws_size,
                              hipStream_t stream) {
    const float* adj   = (const float*)d_in[0];
    const float* feat  = (const float*)d_in[1];
    const float* edgef = (const float*)d_in[2];
    const float* mask  = (const float*)d_in[3];
    const float* W     = (const float*)d_in[4];
    const float* bias  = (const float*)d_in[5];

    float* out   = (float*)d_out;
    float* o_adj = out;
    float* o_res = out + (size_t)16777216;              // 4096*4096
    float* o_out = o_res + (size_t)8388608;             // 16*4096*128
    float* o_m   = o_out + (size_t)8388608;             // + 16*4096*128 -> 4*4096 tail

    unsigned short* wfrag = (unsigned short*)d_ws;      // 73728 * 2 B

    prep_w<<<288, 256, 0, stream>>>(W, wfrag);
    main_k<<<512, 256, 0, stream>>>(feat, edgef, wfrag, bias, mask,
                                    (const floatx4*)adj, (floatx4*)o_adj,
                                    o_res, o_out, o_m);
}